// Round 12
// baseline (185.715 us; speedup 1.0000x reference)
//
#include <hip/hip_runtime.h>
#include <math.h>

#define NT 16
#define NR 25
#define DZ 512
#define D2Z 1024
#define NC 64

typedef short bf16x8 __attribute__((ext_vector_type(8)));
typedef float f32x4  __attribute__((ext_vector_type(4)));

#define TP  76    // convW LDS tile pitch (ushorts)
#define XSP 520   // x LDS pitch (ushorts): 1040B rows, 16B-aligned
#define CP2 36    // C tile pitch (floats), 32 cols + 4 pad

static __device__ inline unsigned short f2bf(float v) {
    union { float f; unsigned u; } x; x.f = v;
    unsigned r = x.u + 0x7fffu + ((x.u >> 16) & 1u);
    return (unsigned short)(r >> 16);
}
static __device__ inline float bf2f(unsigned short h) {
    union { float f; unsigned u; } x; x.u = ((unsigned)h) << 16; return x.f;
}

// ---------------------------------------------------------------------------
// k_prep: blocks 0..383 convW transpose+split (verified), 384..783 distances
// (verified).
// ---------------------------------------------------------------------------
__global__ __launch_bounds__(256) void k_prep(
    const float* __restrict__ x, const float* __restrict__ W1,
    unsigned short* __restrict__ W1h, unsigned short* __restrict__ W1l,
    float* __restrict__ Dm)
{
    __shared__ unsigned short th[64 * TP], tl[64 * TP];
    int vb = blockIdx.x;
    int tid = threadIdx.x;

    if (vb < 384) {
        int r0 = (vb % 24) * 64;
        int j0 = (vb / 24) * 64;
        int c  = r0 >> 9;
        int rb = r0 & 511;

        #pragma unroll
        for (int it = 0; it < 4; it++) {
            int rl = (tid >> 4) + it * 16;
            int jj = (tid & 15) * 4;
            float4 v = *(const float4*)(W1 + (size_t)(r0 + rl) * D2Z + j0 + jj);
            unsigned short h0 = f2bf(v.x), h1 = f2bf(v.y), h2 = f2bf(v.z), h3 = f2bf(v.w);
            th[rl * TP + jj + 0] = h0; tl[rl * TP + jj + 0] = f2bf(v.x - bf2f(h0));
            th[rl * TP + jj + 1] = h1; tl[rl * TP + jj + 1] = f2bf(v.y - bf2f(h1));
            th[rl * TP + jj + 2] = h2; tl[rl * TP + jj + 2] = f2bf(v.z - bf2f(h2));
            th[rl * TP + jj + 3] = h3; tl[rl * TP + jj + 3] = f2bf(v.w - bf2f(h3));
        }
        __syncthreads();

        #pragma unroll
        for (int it = 0; it < 4; it++) {
            int jl = (tid >> 4) + it * 16;
            int r4 = (tid & 15) * 4;
            ushort4 hv = make_ushort4(th[(r4+0)*TP + jl], th[(r4+1)*TP + jl],
                                      th[(r4+2)*TP + jl], th[(r4+3)*TP + jl]);
            ushort4 lv = make_ushort4(tl[(r4+0)*TP + jl], tl[(r4+1)*TP + jl],
                                      tl[(r4+2)*TP + jl], tl[(r4+3)*TP + jl]);
            size_t dst = ((size_t)c * D2Z + j0 + jl) * DZ + rb + r4;
            *(ushort4*)(W1h + dst) = hv;
            *(ushort4*)(W1l + dst) = lv;
        }
    } else {
        int i = vb - 384;
        int k = i & 15, a = i >> 4;
        int lane = tid & 63;
        int w    = tid >> 6;
        const float* xk = x + (size_t)k * NR * DZ;

        const float4* xap = (const float4*)(xk + a * DZ);
        float4 a0 = xap[lane];
        float4 a1 = xap[lane + 64];

        float sa = a0.x*a0.x + a0.y*a0.y + a0.z*a0.z + a0.w*a0.w
                 + a1.x*a1.x + a1.y*a1.y + a1.z*a1.z + a1.w*a1.w;
        #pragma unroll
        for (int off = 32; off; off >>= 1) sa += __shfl_xor(sa, off);
        float inva = 1.0f / sqrtf(sa);
        a0.x *= inva; a0.y *= inva; a0.z *= inva; a0.w *= inva;
        a1.x *= inva; a1.y *= inva; a1.z *= inva; a1.w *= inva;
        float sqa = a0.x*a0.x + a0.y*a0.y + a0.z*a0.z + a0.w*a0.w
                  + a1.x*a1.x + a1.y*a1.y + a1.z*a1.z + a1.w*a1.w;
        #pragma unroll
        for (int off = 32; off; off >>= 1) sqa += __shfl_xor(sqa, off);

        for (int j = w; j < NR; j += 4) {
            const float4* xjp = (const float4*)(xk + j * DZ);
            float4 j0 = xjp[lane];
            float4 j1 = xjp[lane + 64];
            float sj = j0.x*j0.x + j0.y*j0.y + j0.z*j0.z + j0.w*j0.w
                     + j1.x*j1.x + j1.y*j1.y + j1.z*j1.z + j1.w*j1.w;
            #pragma unroll
            for (int off = 32; off; off >>= 1) sj += __shfl_xor(sj, off);
            float invj = 1.0f / sqrtf(sj);
            j0.x *= invj; j0.y *= invj; j0.z *= invj; j0.w *= invj;
            j1.x *= invj; j1.y *= invj; j1.z *= invj; j1.w *= invj;

            float sqj = j0.x*j0.x + j0.y*j0.y + j0.z*j0.z + j0.w*j0.w
                      + j1.x*j1.x + j1.y*j1.y + j1.z*j1.z + j1.w*j1.w;
            float dij = a0.x*j0.x + a0.y*j0.y + a0.z*j0.z + a0.w*j0.w
                      + a1.x*j1.x + a1.y*j1.y + a1.z*j1.z + a1.w*j1.w;
            #pragma unroll
            for (int off = 32; off; off >>= 1) {
                sqj += __shfl_xor(sqj, off);
                dij += __shfl_xor(dij, off);
            }
            float d2 = sqa + sqj - 2.0f * dij;
            float d  = sqrtf(fmaxf(d2, 0.0f));
            if (lane == 0) Dm[((size_t)k * NR + a) * NR + j] = d;
        }
    }
}

// ---------------------------------------------------------------------------
// k_fused v5: 512 blocks = (16 tasks x 32 j-tiles of 32 cols), 2 blocks/CU.
//  - 4 waves = 2 col-halves x 2 K-halves; K-halves write Ct[0]/Ct[1] partials
//    summed in the accum phase (fp32 reassociation only; masks from Dm).
//  - x staged once (inline f2bf split, bit-identical); B direct from global
//    W1h/W1l (no K-loop barriers); XCD swizzle bid%8 == jt%8.
// LDS ~77 KB -> 2 blocks/CU with 512 blocks to fill them (R11 had grid 256 =
// 1 block/CU: half the latency hiding).
// ---------------------------------------------------------------------------
__global__ __launch_bounds__(256, 2) void k_fused(
    const float* __restrict__ x,
    const unsigned short* __restrict__ W1h, const unsigned short* __restrict__ W1l,
    const float* __restrict__ b1, const float* __restrict__ Dm,
    float* __restrict__ G)
{
    __shared__ unsigned short xs_h[25 * XSP], xs_l[25 * XSP];   // 26 KB each
    __shared__ float Ct[2][75 * CP2];                           // 21.6 KB
    __shared__ float Dm_s[NR * NR];
    __shared__ float red[8][32];

    int bid = blockIdx.x;
    int k  = bid >> 5;          // task
    int jt = bid & 31;          // j-tile -> XCD = jt % 8 for all k
    int j0 = jt * 32;

    int tid  = threadIdx.x;
    int lane = tid & 63;
    int w    = tid >> 6;
    int wn   = w & 1;           // col half
    int wk   = w >> 1;          // K half
    int q    = lane >> 4;
    int ln16 = lane & 15;

    for (int idx = tid; idx < NR * NR; idx += 256)
        Dm_s[idx] = Dm[(size_t)k * NR * NR + idx];

    // ---- stage x once: rows 0..24 converted inline (bit-identical split) ----
    for (int g = tid; g < NR * 64; g += 256) {
        int row = g >> 6;
        int c8  = (g & 63) * 8;
        const float* xp = x + ((size_t)k * NR + row) * DZ + c8;
        float4 v0 = *(const float4*)(xp);
        float4 v1 = *(const float4*)(xp + 4);
        unsigned short h;
        ushort4 ha, hb, la, lb;
        h = f2bf(v0.x); ha.x = h; la.x = f2bf(v0.x - bf2f(h));
        h = f2bf(v0.y); ha.y = h; la.y = f2bf(v0.y - bf2f(h));
        h = f2bf(v0.z); ha.z = h; la.z = f2bf(v0.z - bf2f(h));
        h = f2bf(v0.w); ha.w = h; la.w = f2bf(v0.w - bf2f(h));
        h = f2bf(v1.x); hb.x = h; lb.x = f2bf(v1.x - bf2f(h));
        h = f2bf(v1.y); hb.y = h; lb.y = f2bf(v1.y - bf2f(h));
        h = f2bf(v1.z); hb.z = h; lb.z = f2bf(v1.z - bf2f(h));
        h = f2bf(v1.w); hb.w = h; lb.w = f2bf(v1.w - bf2f(h));
        *(ushort4*)&xs_h[row * XSP + c8]     = ha;
        *(ushort4*)&xs_h[row * XSP + c8 + 4] = hb;
        *(ushort4*)&xs_l[row * XSP + c8]     = la;
        *(ushort4*)&xs_l[row * XSP + c8 + 4] = lb;
    }
    __syncthreads();

    int rowA1 = 16 + ln16;
    if (rowA1 > 24) rowA1 = 24;    // pad lanes duplicate row 24 (C rows 25..31 unused)

    // B row for this lane: n = j0 + wn*16 + ln16; K half = wk*256; k-contiguous
    const unsigned short* wb_h = W1h + ((size_t)j0 + wn * 16 + ln16) * DZ + wk * 256 + q * 8;
    const unsigned short* wb_l = W1l + ((size_t)j0 + wn * 16 + ln16) * DZ + wk * 256 + q * 8;

    for (int c = 0; c < 3; c++) {
        f32x4 acc0 = (f32x4){0.f,0.f,0.f,0.f};
        f32x4 acc1 = (f32x4){0.f,0.f,0.f,0.f};
        const unsigned short* wch = wb_h + (size_t)c * D2Z * DZ;
        const unsigned short* wcl = wb_l + (size_t)c * D2Z * DZ;

        #pragma unroll
        for (int kc = 0; kc < 8; kc++) {        // 8 steps of 32-k per K-half
            int kog = wk * 256 + kc * 32 + q * 8;
            bf16x8 b_h = *(const bf16x8*)(wch + kc * 32);
            bf16x8 b_l = *(const bf16x8*)(wcl + kc * 32);
            bf16x8 a0h = *(const bf16x8*)&xs_h[ln16 * XSP + kog];
            bf16x8 a0l = *(const bf16x8*)&xs_l[ln16 * XSP + kog];
            bf16x8 a1h = *(const bf16x8*)&xs_h[rowA1 * XSP + kog];
            bf16x8 a1l = *(const bf16x8*)&xs_l[rowA1 * XSP + kog];
            acc0 = __builtin_amdgcn_mfma_f32_16x16x32_bf16(a0h, b_h, acc0, 0, 0, 0);
            acc0 = __builtin_amdgcn_mfma_f32_16x16x32_bf16(a0h, b_l, acc0, 0, 0, 0);
            acc0 = __builtin_amdgcn_mfma_f32_16x16x32_bf16(a0l, b_h, acc0, 0, 0, 0);
            acc1 = __builtin_amdgcn_mfma_f32_16x16x32_bf16(a1h, b_h, acc1, 0, 0, 0);
            acc1 = __builtin_amdgcn_mfma_f32_16x16x32_bf16(a1h, b_l, acc1, 0, 0, 0);
            acc1 = __builtin_amdgcn_mfma_f32_16x16x32_bf16(a1l, b_h, acc1, 0, 0, 0);
        }

        // epilogue: col = wn*16+ln16, rows q*4+r / 16+q*4+r into K-half partial
        int col = wn * 16 + ln16;
        #pragma unroll
        for (int r = 0; r < 4; r++) {
            int r0 = q * 4 + r;
            Ct[wk][(c * 25 + r0) * CP2 + col] = acc0[r];
            int r1 = 16 + q * 4 + r;
            if (r1 < 25) Ct[wk][(c * 25 + r1) * CP2 + col] = acc1[r];
        }
    }
    __syncthreads();

    // ---- in-block accum: thread = (column j 0..31, subset s 0..7) ----
    // s = (a-parity << 2) | m-index; a strided by 2, m = mi-th valid (!= a/5).
    int j  = tid & 31;
    int s  = tid >> 5;
    int mi = s & 3;
    int ap = s >> 2;
    float b1v = b1[j0 + j];

    float a2v[NR], a3v[NR];
    #pragma unroll
    for (int i = 0; i < NR; i++)
        a2v[i] = Ct[0][(25 + i) * CP2 + j] + Ct[1][(25 + i) * CP2 + j];
    #pragma unroll
    for (int i = 0; i < NR; i++)
        a3v[i] = Ct[0][(50 + i) * CP2 + j] + Ct[1][(50 + i) * CP2 + j];

    float acc = 0.0f;
    for (int a = ap; a < NR; a += 2) {
        const int qa = a % 5, mdiv = a / 5;
        int m = mi + (mi >= mdiv);
        int p = qa + 5 * m;
        float a1  = Ct[0][a * CP2 + j] + Ct[1][a * CP2 + j];
        float dap = Dm_s[a * NR + p];
        float sv = a1 + a2v[p] + b1v;
        #pragma unroll
        for (int ng = 0; ng < 5; ng++) {
            #pragma unroll
            for (int o = 0; o < 4; o++) {
                int n = ng * 5 + o + (o >= qa);
                float tm = Dm_s[a * NR + n] - dap;
                bool sel = (tm > 0.0f) && (tm <= 0.8f);
                float pre = fmaxf(sv + a3v[n], 0.0f);
                float msk = sel ? 1.0f : 0.0f;
                acc = fmaf(msk, pre, acc);
            }
        }
    }
    red[s][j] = acc;
    __syncthreads();
    if (tid < 32) {
        float g = 0.0f;
        #pragma unroll
        for (int t = 0; t < 8; t++) g += red[t][tid];
        G[(size_t)k * D2Z + j0 + tid] = g;
    }
}

// ---------------------------------------------------------------------------
// Tail (verified R9/R11 bodies).
// ---------------------------------------------------------------------------
__global__ __launch_bounds__(256) void k_pooled(const float* __restrict__ G,
                                                const float* __restrict__ Dm,
                                                const float* __restrict__ W2,
                                                const float* __restrict__ b2,
                                                float* __restrict__ pooled)
{
    int bx = blockIdx.x, k = blockIdx.y;
    int tid = threadIdx.x, lane = tid & 63, kc = tid >> 6;
    int col = bx * 64 + lane;

    const float* Dk = Dm + (size_t)k * NR * NR;
    float cntv = 0.0f;
    for (int idx = tid; idx < 2000; idx += 256) {
        int a   = idx / 80;
        int rem = idx - a * 80;
        int mi  = rem / 20;
        int nn  = rem - mi * 20;
        int qa = a % 5, mdiv = a / 5;
        int m = mi + (mi >= mdiv);
        int p = qa + 5 * m;
        int ng = nn >> 2, o = nn & 3;
        int n = ng * 5 + o + (o >= qa);
        float tm = Dk[a * NR + n] - Dk[a * NR + p];
        cntv += ((tm > 0.0f) && (tm <= 0.8f)) ? 1.0f : 0.0f;
    }
    #pragma unroll
    for (int off = 32; off; off >>= 1) cntv += __shfl_xor(cntv, off);

    __shared__ float red[4][64];
    __shared__ float cred[4];
    if (lane == 0) cred[kc] = cntv;

    const float* Gk = G + (size_t)k * D2Z;
    float a0 = 0.f, a1 = 0.f, a2 = 0.f, a3 = 0.f;
    int j0 = kc * 256;
    #pragma unroll 4
    for (int jj = j0; jj < j0 + 256; jj += 4) {
        a0 = fmaf(Gk[jj+0], W2[(size_t)(jj+0) * DZ + col], a0);
        a1 = fmaf(Gk[jj+1], W2[(size_t)(jj+1) * DZ + col], a1);
        a2 = fmaf(Gk[jj+2], W2[(size_t)(jj+2) * DZ + col], a2);
        a3 = fmaf(Gk[jj+3], W2[(size_t)(jj+3) * DZ + col], a3);
    }
    red[kc][lane] = (a0 + a1) + (a2 + a3);
    __syncthreads();
    if (tid < 64) {
        float cnt = cred[0] + cred[1] + cred[2] + cred[3];
        float s = red[0][lane] + red[1][lane] + red[2][lane] + red[3][lane];
        s += cnt * b2[col];
        pooled[(size_t)k * DZ + col] = s;
    }
}

__global__ __launch_bounds__(256) void k_u(const float* __restrict__ pooled,
                                           const float* __restrict__ W3,
                                           const float* __restrict__ b3,
                                           float* __restrict__ u)
{
    int bx = blockIdx.x, k = blockIdx.y;
    int tid = threadIdx.x, lane = tid & 63, kc = tid >> 6;
    int col = bx * 64 + lane;

    const float* Pk = pooled + (size_t)k * DZ;
    float a0 = 0.f, a1 = 0.f, a2 = 0.f, a3 = 0.f;
    int s0 = kc * 128;
    #pragma unroll 4
    for (int s = s0; s < s0 + 128; s += 4) {
        a0 = fmaf(Pk[s+0], W3[(size_t)(s+0) * D2Z + col], a0);
        a1 = fmaf(Pk[s+1], W3[(size_t)(s+1) * D2Z + col], a1);
        a2 = fmaf(Pk[s+2], W3[(size_t)(s+2) * D2Z + col], a2);
        a3 = fmaf(Pk[s+3], W3[(size_t)(s+3) * D2Z + col], a3);
    }
    __shared__ float red[4][64];
    red[kc][lane] = (a0 + a1) + (a2 + a3);
    __syncthreads();
    if (tid < 64) {
        float v = red[0][lane] + red[1][lane] + red[2][lane] + red[3][lane] + b3[col];
        u[(size_t)k * D2Z + col] = fmaxf(v, 0.0f);
    }
}

__global__ __launch_bounds__(256) void k_o(const float* __restrict__ u,
                                           const float* __restrict__ W4,
                                           const float* __restrict__ b4,
                                           float* __restrict__ o)
{
    int bx = blockIdx.x, k = blockIdx.y;
    int tid = threadIdx.x, lane = tid & 63, kc = tid >> 6;
    int col = bx * 64 + lane;

    const float* Uk = u + (size_t)k * D2Z;
    float a0 = 0.f, a1 = 0.f, a2 = 0.f, a3 = 0.f;
    int j0 = kc * 256;
    #pragma unroll 4
    for (int jj = j0; jj < j0 + 256; jj += 4) {
        a0 = fmaf(Uk[jj+0], W4[(size_t)(jj+0) * DZ + col], a0);
        a1 = fmaf(Uk[jj+1], W4[(size_t)(jj+1) * DZ + col], a1);
        a2 = fmaf(Uk[jj+2], W4[(size_t)(jj+2) * DZ + col], a2);
        a3 = fmaf(Uk[jj+3], W4[(size_t)(jj+3) * DZ + col], a3);
    }
    __shared__ float red[4][64];
    red[kc][lane] = (a0 + a1) + (a2 + a3);
    __syncthreads();
    if (tid < 64) {
        o[(size_t)k * DZ + col] = red[0][lane] + red[1][lane] + red[2][lane]
                                + red[3][lane] + b4[col];
    }
}

__global__ __launch_bounds__(256) void k_score(const float* __restrict__ o,
                                               const float* __restrict__ Wc,
                                               const float* __restrict__ bc,
                                               float* __restrict__ out)
{
    int k = blockIdx.x;
    int tid = threadIdx.x, oc = tid & 63, kc = tid >> 6;

    const float* Ok = o + (size_t)k * DZ;
    float a0 = 0.f, a1 = 0.f, a2 = 0.f, a3 = 0.f;
    int r0 = kc * 128;
    #pragma unroll 4
    for (int rr = r0; rr < r0 + 128; rr += 4) {
        a0 = fmaf(Ok[rr+0], Wc[(size_t)(rr+0) * NC + oc], a0);
        a1 = fmaf(Ok[rr+1], Wc[(size_t)(rr+1) * NC + oc], a1);
        a2 = fmaf(Ok[rr+2], Wc[(size_t)(rr+2) * NC + oc], a2);
        a3 = fmaf(Ok[rr+3], Wc[(size_t)(rr+3) * NC + oc], a3);
    }
    __shared__ float red[4][64];
    red[kc][oc] = (a0 + a1) + (a2 + a3);
    __syncthreads();
    if (tid < 64) {
        float sc = bc[tid] + red[0][tid] + red[1][tid] + red[2][tid] + red[3][tid];
        float m = sc;
        #pragma unroll
        for (int off = 32; off; off >>= 1) m = fmaxf(m, __shfl_xor(m, off));
        float e = expf(sc - m);
        float ss = e;
        #pragma unroll
        for (int off = 32; off; off >>= 1) ss += __shfl_xor(ss, off);
        out[k * NC + tid] = e / ss;
    }
}

extern "C" void kernel_launch(void* const* d_in, const int* in_sizes, int n_in,
                              void* d_out, int out_size, void* d_ws, size_t ws_size,
                              hipStream_t stream)
{
    const float* x  = (const float*)d_in[0];
    const float* W1 = (const float*)d_in[1];
    const float* b1 = (const float*)d_in[2];
    const float* W2 = (const float*)d_in[3];
    const float* b2 = (const float*)d_in[4];
    const float* W3 = (const float*)d_in[5];
    const float* b3 = (const float*)d_in[6];
    const float* W4 = (const float*)d_in[7];
    const float* b4 = (const float*)d_in[8];
    const float* Wc = (const float*)d_in[9];
    const float* bc = (const float*)d_in[10];
    float* out = (float*)d_out;

    float* ws     = (float*)d_ws;
    float* Dm     = ws;                       // 10000
    float* G      = ws + 10016;               // 16384 (fully overwritten)
    float* pooled = ws + 26400;               // 8192
    float* uu     = pooled + 8192;            // 16384
    float* oo     = uu + 16384;               // 8192
    unsigned short* W1h = (unsigned short*)(oo + 8192);
    unsigned short* W1l = W1h + 3 * D2Z * DZ;

    k_prep  <<<784,            256, 0, stream>>>(x, W1, W1h, W1l, Dm);
    k_fused <<<512,            256, 0, stream>>>(x, W1h, W1l, b1, Dm, G);
    k_pooled<<<dim3(8, NT),    256, 0, stream>>>(G, Dm, W2, b2, pooled);
    k_u     <<<dim3(16, NT),   256, 0, stream>>>(pooled, W3, b3, uu);
    k_o     <<<dim3(8, NT),    256, 0, stream>>>(uu, W4, b4, oo);
    k_score <<<NT,             256, 0, stream>>>(oo, Wc, bc, out);
}

// Round 13
// 151.323 us; speedup vs baseline: 1.2273x; 1.2273x over previous
//
#include <hip/hip_runtime.h>
#include <math.h>

#define NT 16
#define NR 25
#define DZ 512
#define D2Z 1024
#define NC 64

typedef short bf16x8 __attribute__((ext_vector_type(8)));
typedef float f32x4  __attribute__((ext_vector_type(4)));

#define TP  76    // convW LDS tile pitch (ushorts)
#define XSP 520   // x LDS pitch (ushorts): 1040B rows, 16B-aligned
#define CP  68    // C tile pitch (floats)

static __device__ inline unsigned short f2bf(float v) {
    union { float f; unsigned u; } x; x.f = v;
    unsigned r = x.u + 0x7fffu + ((x.u >> 16) & 1u);
    return (unsigned short)(r >> 16);
}
static __device__ inline float bf2f(unsigned short h) {
    union { float f; unsigned u; } x; x.u = ((unsigned)h) << 16; return x.f;
}

// ---------------------------------------------------------------------------
// k_prep: blocks 0..383 convW transpose+split (verified), 384..783 distances
// (verified).
// ---------------------------------------------------------------------------
__global__ __launch_bounds__(256) void k_prep(
    const float* __restrict__ x, const float* __restrict__ W1,
    unsigned short* __restrict__ W1h, unsigned short* __restrict__ W1l,
    float* __restrict__ Dm)
{
    __shared__ unsigned short th[64 * TP], tl[64 * TP];
    int vb = blockIdx.x;
    int tid = threadIdx.x;

    if (vb < 384) {
        int r0 = (vb % 24) * 64;
        int j0 = (vb / 24) * 64;
        int c  = r0 >> 9;
        int rb = r0 & 511;

        #pragma unroll
        for (int it = 0; it < 4; it++) {
            int rl = (tid >> 4) + it * 16;
            int jj = (tid & 15) * 4;
            float4 v = *(const float4*)(W1 + (size_t)(r0 + rl) * D2Z + j0 + jj);
            unsigned short h0 = f2bf(v.x), h1 = f2bf(v.y), h2 = f2bf(v.z), h3 = f2bf(v.w);
            th[rl * TP + jj + 0] = h0; tl[rl * TP + jj + 0] = f2bf(v.x - bf2f(h0));
            th[rl * TP + jj + 1] = h1; tl[rl * TP + jj + 1] = f2bf(v.y - bf2f(h1));
            th[rl * TP + jj + 2] = h2; tl[rl * TP + jj + 2] = f2bf(v.z - bf2f(h2));
            th[rl * TP + jj + 3] = h3; tl[rl * TP + jj + 3] = f2bf(v.w - bf2f(h3));
        }
        __syncthreads();

        #pragma unroll
        for (int it = 0; it < 4; it++) {
            int jl = (tid >> 4) + it * 16;
            int r4 = (tid & 15) * 4;
            ushort4 hv = make_ushort4(th[(r4+0)*TP + jl], th[(r4+1)*TP + jl],
                                      th[(r4+2)*TP + jl], th[(r4+3)*TP + jl]);
            ushort4 lv = make_ushort4(tl[(r4+0)*TP + jl], tl[(r4+1)*TP + jl],
                                      tl[(r4+2)*TP + jl], tl[(r4+3)*TP + jl]);
            size_t dst = ((size_t)c * D2Z + j0 + jl) * DZ + rb + r4;
            *(ushort4*)(W1h + dst) = hv;
            *(ushort4*)(W1l + dst) = lv;
        }
    } else {
        int i = vb - 384;
        int k = i & 15, a = i >> 4;
        int lane = tid & 63;
        int w    = tid >> 6;
        const float* xk = x + (size_t)k * NR * DZ;

        const float4* xap = (const float4*)(xk + a * DZ);
        float4 a0 = xap[lane];
        float4 a1 = xap[lane + 64];

        float sa = a0.x*a0.x + a0.y*a0.y + a0.z*a0.z + a0.w*a0.w
                 + a1.x*a1.x + a1.y*a1.y + a1.z*a1.z + a1.w*a1.w;
        #pragma unroll
        for (int off = 32; off; off >>= 1) sa += __shfl_xor(sa, off);
        float inva = 1.0f / sqrtf(sa);
        a0.x *= inva; a0.y *= inva; a0.z *= inva; a0.w *= inva;
        a1.x *= inva; a1.y *= inva; a1.z *= inva; a1.w *= inva;
        float sqa = a0.x*a0.x + a0.y*a0.y + a0.z*a0.z + a0.w*a0.w
                  + a1.x*a1.x + a1.y*a1.y + a1.z*a1.z + a1.w*a1.w;
        #pragma unroll
        for (int off = 32; off; off >>= 1) sqa += __shfl_xor(sqa, off);

        for (int j = w; j < NR; j += 4) {
            const float4* xjp = (const float4*)(xk + j * DZ);
            float4 j0 = xjp[lane];
            float4 j1 = xjp[lane + 64];
            float sj = j0.x*j0.x + j0.y*j0.y + j0.z*j0.z + j0.w*j0.w
                     + j1.x*j1.x + j1.y*j1.y + j1.z*j1.z + j1.w*j1.w;
            #pragma unroll
            for (int off = 32; off; off >>= 1) sj += __shfl_xor(sj, off);
            float invj = 1.0f / sqrtf(sj);
            j0.x *= invj; j0.y *= invj; j0.z *= invj; j0.w *= invj;
            j1.x *= invj; j1.y *= invj; j1.z *= invj; j1.w *= invj;

            float sqj = j0.x*j0.x + j0.y*j0.y + j0.z*j0.z + j0.w*j0.w
                      + j1.x*j1.x + j1.y*j1.y + j1.z*j1.z + j1.w*j1.w;
            float dij = a0.x*j0.x + a0.y*j0.y + a0.z*j0.z + a0.w*j0.w
                      + a1.x*j1.x + a1.y*j1.y + a1.z*j1.z + a1.w*j1.w;
            #pragma unroll
            for (int off = 32; off; off >>= 1) {
                sqj += __shfl_xor(sqj, off);
                dij += __shfl_xor(dij, off);
            }
            float d2 = sqa + sqj - 2.0f * dij;
            float d  = sqrtf(fmaxf(d2, 0.0f));
            if (lane == 0) Dm[((size_t)k * NR + a) * NR + j] = d;
        }
    }
}

// ---------------------------------------------------------------------------
// k_fused (R11-verified): per (task k, 64-col j-tile) GEMM+accum.
//  - x staged ONCE (25 rows, inline f2bf split; pad A rows clamp to row 24).
//  - B fragments loaded DIRECTLY from global W1h/W1l (k-contiguous rows):
//    no W LDS, no K-loop barriers.
//  - Accum phase fully compile-time unrolled (R12 lesson: runtime a-indexing
//    explodes VALU 5x via div/mod).
//  - XCD swizzle bid = k*16+jt keeps each j-tile's W in one XCD's L2.
// ---------------------------------------------------------------------------
__global__ __launch_bounds__(256, 2) void k_fused(
    const float* __restrict__ x,
    const unsigned short* __restrict__ W1h, const unsigned short* __restrict__ W1l,
    const float* __restrict__ b1, const float* __restrict__ Dm,
    float* __restrict__ G)
{
    __shared__ unsigned short xs_h[25 * XSP], xs_l[25 * XSP];   // 26 KB each
    __shared__ float Ct[75 * CP];                               // 20.4 KB
    __shared__ float Dm_s[NR * NR];
    __shared__ float red[4][64];

    int bid = blockIdx.x;
    int k  = bid >> 4;          // task
    int jt = bid & 15;          // j-tile -> XCD = jt % 8 for all k
    int j0 = jt * 64;

    int tid  = threadIdx.x;
    int lane = tid & 63;
    int w    = tid >> 6;
    int q    = lane >> 4;
    int ln16 = lane & 15;

    for (int idx = tid; idx < NR * NR; idx += 256)
        Dm_s[idx] = Dm[(size_t)k * NR * NR + idx];

    // ---- stage x once: rows 0..24 converted inline (bit-identical split) ----
    for (int g = tid; g < NR * 64; g += 256) {
        int row = g >> 6;
        int c8  = (g & 63) * 8;
        const float* xp = x + ((size_t)k * NR + row) * DZ + c8;
        float4 v0 = *(const float4*)(xp);
        float4 v1 = *(const float4*)(xp + 4);
        unsigned short h;
        ushort4 ha, hb, la, lb;
        h = f2bf(v0.x); ha.x = h; la.x = f2bf(v0.x - bf2f(h));
        h = f2bf(v0.y); ha.y = h; la.y = f2bf(v0.y - bf2f(h));
        h = f2bf(v0.z); ha.z = h; la.z = f2bf(v0.z - bf2f(h));
        h = f2bf(v0.w); ha.w = h; la.w = f2bf(v0.w - bf2f(h));
        h = f2bf(v1.x); hb.x = h; lb.x = f2bf(v1.x - bf2f(h));
        h = f2bf(v1.y); hb.y = h; lb.y = f2bf(v1.y - bf2f(h));
        h = f2bf(v1.z); hb.z = h; lb.z = f2bf(v1.z - bf2f(h));
        h = f2bf(v1.w); hb.w = h; lb.w = f2bf(v1.w - bf2f(h));
        *(ushort4*)&xs_h[row * XSP + c8]     = ha;
        *(ushort4*)&xs_h[row * XSP + c8 + 4] = hb;
        *(ushort4*)&xs_l[row * XSP + c8]     = la;
        *(ushort4*)&xs_l[row * XSP + c8 + 4] = lb;
    }
    __syncthreads();

    int rowA1 = 16 + ln16;
    if (rowA1 > 24) rowA1 = 24;    // pad lanes duplicate row 24 (C rows 25..31 unused)

    // B row for this lane: n = j0 + w*16 + ln16, k-contiguous
    const unsigned short* wb_h = W1h + ((size_t)j0 + w * 16 + ln16) * DZ + q * 8;
    const unsigned short* wb_l = W1l + ((size_t)j0 + w * 16 + ln16) * DZ + q * 8;

    for (int c = 0; c < 3; c++) {
        f32x4 acc0 = (f32x4){0.f,0.f,0.f,0.f};
        f32x4 acc1 = (f32x4){0.f,0.f,0.f,0.f};
        const unsigned short* wch = wb_h + (size_t)c * D2Z * DZ;
        const unsigned short* wcl = wb_l + (size_t)c * D2Z * DZ;

        #pragma unroll
        for (int kc = 0; kc < 16; kc++) {       // 16 steps of 32-k, no barriers
            int kog = kc * 32 + q * 8;
            bf16x8 b_h = *(const bf16x8*)(wch + kc * 32);
            bf16x8 b_l = *(const bf16x8*)(wcl + kc * 32);
            bf16x8 a0h = *(const bf16x8*)&xs_h[ln16 * XSP + kog];
            bf16x8 a0l = *(const bf16x8*)&xs_l[ln16 * XSP + kog];
            bf16x8 a1h = *(const bf16x8*)&xs_h[rowA1 * XSP + kog];
            bf16x8 a1l = *(const bf16x8*)&xs_l[rowA1 * XSP + kog];
            acc0 = __builtin_amdgcn_mfma_f32_16x16x32_bf16(a0h, b_h, acc0, 0, 0, 0);
            acc0 = __builtin_amdgcn_mfma_f32_16x16x32_bf16(a0h, b_l, acc0, 0, 0, 0);
            acc0 = __builtin_amdgcn_mfma_f32_16x16x32_bf16(a0l, b_h, acc0, 0, 0, 0);
            acc1 = __builtin_amdgcn_mfma_f32_16x16x32_bf16(a1h, b_h, acc1, 0, 0, 0);
            acc1 = __builtin_amdgcn_mfma_f32_16x16x32_bf16(a1h, b_l, acc1, 0, 0, 0);
            acc1 = __builtin_amdgcn_mfma_f32_16x16x32_bf16(a1l, b_h, acc1, 0, 0, 0);
        }

        // epilogue: col = w*16+ln16, row = q*4+r (acc0) / 16+q*4+r (acc1)
        int col = w * 16 + ln16;
        #pragma unroll
        for (int r = 0; r < 4; r++) {
            int r0 = q * 4 + r;
            Ct[(c * 25 + r0) * CP + col] = acc0[r];
            int r1 = 16 + q * 4 + r;
            if (r1 < 25) Ct[(c * 25 + r1) * CP + col] = acc1[r];
        }
    }
    __syncthreads();

    // ---- in-block accum: thread = (column j, valid-m index h) ----
    int j = tid & 63;
    int h = tid >> 6;
    float b1v = b1[j0 + j];

    float a2v[NR], a3v[NR];
    #pragma unroll
    for (int i = 0; i < NR; i++) a2v[i] = Ct[(25 + i) * CP + j];
    #pragma unroll
    for (int i = 0; i < NR; i++) a3v[i] = Ct[(50 + i) * CP + j];

    float acc = 0.0f;
    #pragma unroll
    for (int a = 0; a < NR; a++) {
        const int qa = a % 5, mdiv = a / 5;
        int m = h + (h >= mdiv);
        int p = qa + 5 * m;
        float a1  = Ct[a * CP + j];
        float dap = Dm_s[a * NR + p];
        float s = a1 + a2v[p] + b1v;
        #pragma unroll
        for (int ng = 0; ng < 5; ng++) {
            #pragma unroll
            for (int o = 0; o < 4; o++) {
                int n = ng * 5 + o + (o >= qa);
                float tm = Dm_s[a * NR + n] - dap;
                bool sel = (tm > 0.0f) && (tm <= 0.8f);
                float pre = fmaxf(s + a3v[n], 0.0f);
                float msk = sel ? 1.0f : 0.0f;
                acc = fmaf(msk, pre, acc);
            }
        }
    }
    red[h][j] = acc;
    __syncthreads();
    if (tid < 64)
        G[(size_t)k * D2Z + j0 + tid] = red[0][tid] + red[1][tid]
                                      + red[2][tid] + red[3][tid];
}

// ---------------------------------------------------------------------------
// Tail (verified R9/R11 bodies).
// ---------------------------------------------------------------------------
__global__ __launch_bounds__(256) void k_pooled(const float* __restrict__ G,
                                                const float* __restrict__ Dm,
                                                const float* __restrict__ W2,
                                                const float* __restrict__ b2,
                                                float* __restrict__ pooled)
{
    int bx = blockIdx.x, k = blockIdx.y;
    int tid = threadIdx.x, lane = tid & 63, kc = tid >> 6;
    int col = bx * 64 + lane;

    const float* Dk = Dm + (size_t)k * NR * NR;
    float cntv = 0.0f;
    for (int idx = tid; idx < 2000; idx += 256) {
        int a   = idx / 80;
        int rem = idx - a * 80;
        int mi  = rem / 20;
        int nn  = rem - mi * 20;
        int qa = a % 5, mdiv = a / 5;
        int m = mi + (mi >= mdiv);
        int p = qa + 5 * m;
        int ng = nn >> 2, o = nn & 3;
        int n = ng * 5 + o + (o >= qa);
        float tm = Dk[a * NR + n] - Dk[a * NR + p];
        cntv += ((tm > 0.0f) && (tm <= 0.8f)) ? 1.0f : 0.0f;
    }
    #pragma unroll
    for (int off = 32; off; off >>= 1) cntv += __shfl_xor(cntv, off);

    __shared__ float red[4][64];
    __shared__ float cred[4];
    if (lane == 0) cred[kc] = cntv;

    const float* Gk = G + (size_t)k * D2Z;
    float a0 = 0.f, a1 = 0.f, a2 = 0.f, a3 = 0.f;
    int j0 = kc * 256;
    #pragma unroll 4
    for (int jj = j0; jj < j0 + 256; jj += 4) {
        a0 = fmaf(Gk[jj+0], W2[(size_t)(jj+0) * DZ + col], a0);
        a1 = fmaf(Gk[jj+1], W2[(size_t)(jj+1) * DZ + col], a1);
        a2 = fmaf(Gk[jj+2], W2[(size_t)(jj+2) * DZ + col], a2);
        a3 = fmaf(Gk[jj+3], W2[(size_t)(jj+3) * DZ + col], a3);
    }
    red[kc][lane] = (a0 + a1) + (a2 + a3);
    __syncthreads();
    if (tid < 64) {
        float cnt = cred[0] + cred[1] + cred[2] + cred[3];
        float s = red[0][lane] + red[1][lane] + red[2][lane] + red[3][lane];
        s += cnt * b2[col];
        pooled[(size_t)k * DZ + col] = s;
    }
}

__global__ __launch_bounds__(256) void k_u(const float* __restrict__ pooled,
                                           const float* __restrict__ W3,
                                           const float* __restrict__ b3,
                                           float* __restrict__ u)
{
    int bx = blockIdx.x, k = blockIdx.y;
    int tid = threadIdx.x, lane = tid & 63, kc = tid >> 6;
    int col = bx * 64 + lane;

    const float* Pk = pooled + (size_t)k * DZ;
    float a0 = 0.f, a1 = 0.f, a2 = 0.f, a3 = 0.f;
    int s0 = kc * 128;
    #pragma unroll 4
    for (int s = s0; s < s0 + 128; s += 4) {
        a0 = fmaf(Pk[s+0], W3[(size_t)(s+0) * D2Z + col], a0);
        a1 = fmaf(Pk[s+1], W3[(size_t)(s+1) * D2Z + col], a1);
        a2 = fmaf(Pk[s+2], W3[(size_t)(s+2) * D2Z + col], a2);
        a3 = fmaf(Pk[s+3], W3[(size_t)(s+3) * D2Z + col], a3);
    }
    __shared__ float red[4][64];
    red[kc][lane] = (a0 + a1) + (a2 + a3);
    __syncthreads();
    if (tid < 64) {
        float v = red[0][lane] + red[1][lane] + red[2][lane] + red[3][lane] + b3[col];
        u[(size_t)k * D2Z + col] = fmaxf(v, 0.0f);
    }
}

__global__ __launch_bounds__(256) void k_o(const float* __restrict__ u,
                                           const float* __restrict__ W4,
                                           const float* __restrict__ b4,
                                           float* __restrict__ o)
{
    int bx = blockIdx.x, k = blockIdx.y;
    int tid = threadIdx.x, lane = tid & 63, kc = tid >> 6;
    int col = bx * 64 + lane;

    const float* Uk = u + (size_t)k * D2Z;
    float a0 = 0.f, a1 = 0.f, a2 = 0.f, a3 = 0.f;
    int j0 = kc * 256;
    #pragma unroll 4
    for (int jj = j0; jj < j0 + 256; jj += 4) {
        a0 = fmaf(Uk[jj+0], W4[(size_t)(jj+0) * DZ + col], a0);
        a1 = fmaf(Uk[jj+1], W4[(size_t)(jj+1) * DZ + col], a1);
        a2 = fmaf(Uk[jj+2], W4[(size_t)(jj+2) * DZ + col], a2);
        a3 = fmaf(Uk[jj+3], W4[(size_t)(jj+3) * DZ + col], a3);
    }
    __shared__ float red[4][64];
    red[kc][lane] = (a0 + a1) + (a2 + a3);
    __syncthreads();
    if (tid < 64) {
        o[(size_t)k * DZ + col] = red[0][lane] + red[1][lane] + red[2][lane]
                                + red[3][lane] + b4[col];
    }
}

__global__ __launch_bounds__(256) void k_score(const float* __restrict__ o,
                                               const float* __restrict__ Wc,
                                               const float* __restrict__ bc,
                                               float* __restrict__ out)
{
    int k = blockIdx.x;
    int tid = threadIdx.x, oc = tid & 63, kc = tid >> 6;

    const float* Ok = o + (size_t)k * DZ;
    float a0 = 0.f, a1 = 0.f, a2 = 0.f, a3 = 0.f;
    int r0 = kc * 128;
    #pragma unroll 4
    for (int rr = r0; rr < r0 + 128; rr += 4) {
        a0 = fmaf(Ok[rr+0], Wc[(size_t)(rr+0) * NC + oc], a0);
        a1 = fmaf(Ok[rr+1], Wc[(size_t)(rr+1) * NC + oc], a1);
        a2 = fmaf(Ok[rr+2], Wc[(size_t)(rr+2) * NC + oc], a2);
        a3 = fmaf(Ok[rr+3], Wc[(size_t)(rr+3) * NC + oc], a3);
    }
    __shared__ float red[4][64];
    red[kc][oc] = (a0 + a1) + (a2 + a3);
    __syncthreads();
    if (tid < 64) {
        float sc = bc[tid] + red[0][tid] + red[1][tid] + red[2][tid] + red[3][tid];
        float m = sc;
        #pragma unroll
        for (int off = 32; off; off >>= 1) m = fmaxf(m, __shfl_xor(m, off));
        float e = expf(sc - m);
        float ss = e;
        #pragma unroll
        for (int off = 32; off; off >>= 1) ss += __shfl_xor(ss, off);
        out[k * NC + tid] = e / ss;
    }
}

extern "C" void kernel_launch(void* const* d_in, const int* in_sizes, int n_in,
                              void* d_out, int out_size, void* d_ws, size_t ws_size,
                              hipStream_t stream)
{
    const float* x  = (const float*)d_in[0];
    const float* W1 = (const float*)d_in[1];
    const float* b1 = (const float*)d_in[2];
    const float* W2 = (const float*)d_in[3];
    const float* b2 = (const float*)d_in[4];
    const float* W3 = (const float*)d_in[5];
    const float* b3 = (const float*)d_in[6];
    const float* W4 = (const float*)d_in[7];
    const float* b4 = (const float*)d_in[8];
    const float* Wc = (const float*)d_in[9];
    const float* bc = (const float*)d_in[10];
    float* out = (float*)d_out;

    float* ws     = (float*)d_ws;
    float* Dm     = ws;                       // 10000
    float* G      = ws + 10016;               // 16384 (fully overwritten)
    float* pooled = ws + 26400;               // 8192
    float* uu     = pooled + 8192;            // 16384
    float* oo     = uu + 16384;               // 8192
    unsigned short* W1h = (unsigned short*)(oo + 8192);
    unsigned short* W1l = W1h + 3 * D2Z * DZ;

    k_prep  <<<784,            256, 0, stream>>>(x, W1, W1h, W1l, Dm);
    k_fused <<<256,            256, 0, stream>>>(x, W1h, W1l, b1, Dm, G);
    k_pooled<<<dim3(8, NT),    256, 0, stream>>>(G, Dm, W2, b2, pooled);
    k_u     <<<dim3(16, NT),   256, 0, stream>>>(pooled, W3, b3, uu);
    k_o     <<<dim3(8, NT),    256, 0, stream>>>(uu, W4, b4, oo);
    k_score <<<NT,             256, 0, stream>>>(oo, Wc, bc, out);
}